// Round 9
// baseline (374.630 us; speedup 1.0000x reference)
//
#include <hip/hip_runtime.h>
#include <hip/hip_bf16.h>
#include <hip/hip_fp16.h>

// Codebook argmin: x (32768,512) fp32, codebook (8192,512) fp32 -> codes (32768) int32
//
// v16: v15 (A-in-registers, B-streamed) + counted-vmcnt pipeline. Across
// v7-v15 MfmaUtil pinned at ~23% because __syncthreads drains vmcnt(0),
// exposing the just-issued prefetch's L2 latency every chunk. v16: triple
// buffer, depth-3, raw s_barrier + s_waitcnt vmcnt(2) (loads stay in
// flight across barriers). All vmcnt perturbations removed/strict-safe:
// cn panel in LDS (lgkm), A-loads older than staging (over-waited only),
// part stores strictness-only, wrap-around dummy issues keep in-flight
// exactly 3 through the tail. Math identical to v15 (absmax 0).
//
// ws layout:
//   ch8  : fp8 [8192][512]   @ 0        (4 MB)
//   xh8  : fp8 [32768][512]  @ 4 MB     (16 MB)
//   cnh  : f32 [8192]        @ 20 MB    (32 KB)
//   cand : int [32768][8]    @ 20M+32K  (1 MB)
//   part : uint4 [32][32768] @ 22 MB    (16 MB)

#define M_ROWS 32768
#define DDIM   512
#define KCODES 8192
#define NCAND  8

typedef unsigned long long u64;
typedef unsigned int u32;
typedef __attribute__((ext_vector_type(4))) float f32x4;
typedef __attribute__((ext_vector_type(8))) int v8i;

#define GL2LDS(gp, lp) __builtin_amdgcn_global_load_lds(                  \
    (const __attribute__((address_space(1))) void*)(gp),                  \
    (__attribute__((address_space(3))) void*)(lp), 16, 0, 0)

#define WAITV2() asm volatile("s_waitcnt vmcnt(2)" ::: "memory")
#define WAITL()  asm volatile("s_waitcnt lgkmcnt(0)" ::: "memory")
#define SBAR()   __builtin_amdgcn_sched_barrier(0)
#define BAR() do { SBAR(); __builtin_amdgcn_s_barrier(); SBAR(); } while (0)

__device__ __forceinline__ u32 umin32(u32 a, u32 b) { return a < b ? a : b; }
__device__ __forceinline__ u32 umax32(u32 a, u32 b) { return a > b ? a : b; }
__device__ __forceinline__ u64 umin64(u64 a, u64 b) { return a < b ? a : b; }
__device__ __forceinline__ u32 umin3(u32 a, u32 b, u32 c) {  // fuses to v_min3_u32
  return umin32(umin32(a, b), c);
}
__device__ __forceinline__ u32 med3u(u32 a, u32 b, u32 c) {
  u32 d;
  asm("v_med3_u32 %0, %1, %2, %3" : "=v"(d) : "v"(a), "v"(b), "v"(c));
  return d;
}

// float -> order-preserving u32 (ascending); used only in rescore
__device__ __forceinline__ u32 fsort(float s) {
  u32 fb = __float_as_uint(s);
  return fb ^ (u32)(((int)fb >> 31) | 0x80000000);
}

// 8 floats -> 8 packed e4m3 bytes (uint2)
__device__ __forceinline__ uint2 pk8_fp8(float4 v0, float4 v1) {
  int lo = 0, hi = 0;
  lo = __builtin_amdgcn_cvt_pk_fp8_f32(v0.x, v0.y, lo, false);
  lo = __builtin_amdgcn_cvt_pk_fp8_f32(v0.z, v0.w, lo, true);
  hi = __builtin_amdgcn_cvt_pk_fp8_f32(v1.x, v1.y, hi, false);
  hi = __builtin_amdgcn_cvt_pk_fp8_f32(v1.z, v1.w, hi, true);
  return (uint2){(u32)lo, (u32)hi};
}

// ---------------------------------------------------------------- conv codebook
__global__ __launch_bounds__(256) void conv_codebook_kernel(
    const float* __restrict__ cb, unsigned char* __restrict__ ch8,
    float* __restrict__ cnh) {
  int wave = (blockIdx.x * 256 + threadIdx.x) >> 6;
  int lane = threadIdx.x & 63;
  if (wave >= KCODES) return;
  const float* src = cb + (size_t)wave * DDIM + lane * 8;
  float4 v0 = *(const float4*)(src);
  float4 v1 = *(const float4*)(src + 4);
  *(uint2*)(ch8 + (size_t)wave * DDIM + lane * 8) = pk8_fp8(v0, v1);
  float ss = v0.x*v0.x + v0.y*v0.y + v0.z*v0.z + v0.w*v0.w
           + v1.x*v1.x + v1.y*v1.y + v1.z*v1.z + v1.w*v1.w;
#pragma unroll
  for (int off = 32; off; off >>= 1) ss += __shfl_xor(ss, off);
  if (lane == 0) cnh[wave] = 0.5f * ss;
}

// ---------------------------------------------------------------- conv x
__global__ __launch_bounds__(256) void conv_x_kernel(
    const float* __restrict__ x, unsigned char* __restrict__ xh8) {
  size_t i = ((size_t)blockIdx.x * 256 + threadIdx.x) * 8;
  float4 v0 = *(const float4*)(x + i);
  float4 v1 = *(const float4*)(x + i + 4);
  *(uint2*)(xh8 + i) = pk8_fp8(v0, v1);
}

// ---------------------------------------------------------------- coarse GEMM
// Block: 512 thr = 8 waves as 4x2 (wm,wn); wave tile 32 rows x 32 cols as
// 2x2 grid of 16x16x128 scaled-fp8 MFMA (scales=1.0 -> exact e4m3 math).
// A (32 rows x K512 per wave) in 64 VGPRs, loaded once from global.
// B: 64 chunks of 8KB (16 steps x 4), TRIPLE-buffered, depth-3 prefetch,
// s_waitcnt vmcnt(2) + raw s_barrier (no vmcnt(0) drain in the loop).
// LDS[code][slot] = global[code][slot ^ (code&7)] (granule XOR swizzle).
__global__ __launch_bounds__(512, 4) void coarse_kernel(
    const unsigned char* __restrict__ xh8, const unsigned char* __restrict__ ch8,
    const float* __restrict__ cnh, uint4* __restrict__ part) {
  // bufs 3x8192 @0; cnL f32[1024] @24576; tab uint2[128*17] @28672.
  // Total 46080 B -> 3 blocks/CU.
  __shared__ __align__(16) char smem[46080];
  float* cnL = (float*)(smem + 24576);
  uint2* tab = (uint2*)(smem + 28672);

  const int tid  = threadIdx.x;
  const int lane = tid & 63;
  const int wid  = tid >> 6;
  const int wm   = wid >> 1, wn = wid & 1;   // 4 x 2 waves
  const int g    = lane >> 4, l16 = lane & 15;

  // blockIdx = mblk*8 + ngrp: round-robin puts ngrp==XCD -> each XCD keeps
  // one 1024-col B panel (512 KB) L2-resident.
  const int mblk = blockIdx.x >> 3;
  const int ngrp = blockIdx.x & 7;
  const int row0 = mblk * 128;
  const int colgrp = ngrp * 1024;

  // ---- A in registers: rows row0 + wm*32 + tm*16 + l16, full K ----
  v8i A[2][4];
#pragma unroll
  for (int tm = 0; tm < 2; ++tm) {
    const unsigned char* ap =
        xh8 + (size_t)(row0 + wm * 32 + tm * 16 + l16) * DDIM + g * 32;
#pragma unroll
    for (int c = 0; c < 4; ++c) {
      int4 lo = *(const int4*)(ap + c * 128);
      int4 hi = *(const int4*)(ap + c * 128 + 16);
      A[tm][c][0] = lo.x; A[tm][c][1] = lo.y; A[tm][c][2] = lo.z; A[tm][c][3] = lo.w;
      A[tm][c][4] = hi.x; A[tm][c][5] = hi.y; A[tm][c][6] = hi.z; A[tm][c][7] = hi.w;
    }
  }

  // ---- cn panel -> LDS (read in epilogue via ds_read: lgkm, not vmcnt) ----
  if (tid < 256)
    *(float4*)(cnL + tid * 4) = *(const float4*)(cnh + colgrp + tid * 4);

  // ---- B staging geometry: thread -> (code, granule) ----
  const int scode = tid >> 3;                       // 0..63
  const int sgran = (tid & 7) ^ (scode & 7);        // XOR swizzle
  const unsigned char* bsrc =
      ch8 + (size_t)(colgrp + scode) * DDIM + sgran * 16;
  char* ldst = smem + tid * 16;                     // + buf*8192

  // ---- per-lane B read offsets: row = wn*32 + tn*16 + l16 ----
  const int boff = (wn * 32 + l16) * 128 + (((g * 2) ^ (l16 & 7)) << 4);

  u32 m1 = ~0u, m2 = ~0u, m3 = ~0u;   // running top-3 per 256-col slice

  // prologue: issue chunks 0,1,2 (newest 3 vmem ops; A/cn loads are older
  // and retire under the first vmcnt(2) -- strictness-safe).
  SBAR();
  GL2LDS(bsrc +   0, ldst);
  GL2LDS(bsrc + 128, ldst + 8192);
  GL2LDS(bsrc + 256, ldst + 16384);
  SBAR();
  WAITL();                            // cn ds_write committed

  int bsel = 0;                       // nb % 3
  for (int nb = 0; nb < 16; ++nb) {
    f32x4 acc[2][2];
#pragma unroll
    for (int tm = 0; tm < 2; ++tm)
#pragma unroll
      for (int tn = 0; tn < 2; ++tn) acc[tm][tn] = (f32x4){0.f, 0.f, 0.f, 0.f};

#pragma unroll
    for (int c = 0; c < 4; ++c) {     // chunk t = nb*4 + c; buffer (nb+c)%3
      int rb = bsel + c; if (rb >= 3) rb -= 3;
      WAITV2();                       // own ld(t) landed; t+1, t+2 in flight
      BAR();                          // all waves' ld(t) landed
      const char* bL = smem + rb * 8192;
#pragma unroll
      for (int tn = 0; tn < 2; ++tn) {
        int4 lo = *(const int4*)(bL + boff + tn * 2048);
        int4 hi = *(const int4*)(bL + ((boff + tn * 2048) ^ 16));
        v8i bf;
        bf[0] = lo.x; bf[1] = lo.y; bf[2] = lo.z; bf[3] = lo.w;
        bf[4] = hi.x; bf[5] = hi.y; bf[6] = hi.z; bf[7] = hi.w;
#pragma unroll
        for (int tm = 0; tm < 2; ++tm)
          acc[tm][tn] = __builtin_amdgcn_mfma_scale_f32_16x16x128_f8f6f4(
              A[tm][c], bf, acc[tm][tn],
              0, 0,                     // cbsz=fp8(e4m3), blgp=fp8(e4m3)
              0, 0x7F7F7F7F,            // opsel_a, scale_a = 1.0 (E8M0 127)
              0, 0x7F7F7F7F);           // opsel_b, scale_b = 1.0
      }
      WAITL();
      BAR();                          // all waves done reading buf rb
      // issue ld(t+3) into the SAME buffer ((t+3)%3 == t%3). For t>=61
      // this wraps into step-0 addresses (valid ws memory, never read):
      // keeps in-flight count at exactly 3 so WAITV2 is uniform.
      GL2LDS(bsrc + (c == 0 ? 384 : 32768 + (c - 1) * 128), ldst + rb * 8192);
      SBAR();
    }

    // ---- step epilogue: lazy keys -> uint2 tab, 2 wn passes ----
    // key = float_bits(s) & ~0x1FFF | code (s > 0 by 8-sigma margin).
    const int col0 = colgrp + nb * 64;
#pragma unroll
    for (int p = 0; p < 2; ++p) {
      if (wn == p) {
        u32 codev[2];
        float cnv[2];
#pragma unroll
        for (int tn = 0; tn < 2; ++tn) {
          codev[tn] = (u32)(col0 + wn * 32 + tn * 16 + l16);
          cnv[tn] = cnL[nb * 64 + wn * 32 + tn * 16 + l16];
        }
#pragma unroll
        for (int tm = 0; tm < 2; ++tm)
#pragma unroll
          for (int r = 0; r < 4; ++r) {
            float s0 = cnv[0] - acc[tm][0][r];
            float s1 = cnv[1] - acc[tm][1][r];
            u32 key0 = (__float_as_uint(s0) & 0xFFFFE000u) | codev[0];
            u32 key1 = (__float_as_uint(s1) & 0xFFFFE000u) | codev[1];
            const int row = wm * 32 + tm * 16 + g * 4 + r;
            tab[row * 17 + l16] = (uint2){umin32(key0, key1), umax32(key0, key1)};
          }
      }
      WAITL();                        // tab writes committed
      BAR();
      if (tid < 128) {
        // merge sorted pair {x<=y} into running {m1<=m2<=m3}:
        //   a = max(m1,x); m1' = min(m1,x);
        //   b = med3(m2,a,y); m2' = min3(m2,a,y); m3' = min(m3,b).
#pragma unroll
        for (int e = 0; e < 16; ++e) {
          uint2 v = tab[tid * 17 + e];
          u32 a = umax32(m1, v.x);
          m1 = umin32(m1, v.x);
          u32 b = med3u(m2, a, v.y);
          m2 = umin3(m2, a, v.y);
          m3 = umin32(m3, b);
        }
      }
      BAR();                          // tab consumed; next pass may write
    }

    if ((nb & 3) == 3) {              // end of 256-col slice
      if (tid < 128) {
        // vmem store: only ADDS vmcnt strictness (never looseness).
        part[(size_t)(ngrp * 4 + (nb >> 2)) * M_ROWS + row0 + tid] =
            (uint4){m1, m2, m3, 0u};
        m1 = ~0u; m2 = ~0u; m3 = ~0u;
      }
    }
    bsrc += 32768;                    // next 64-col step
    bsel = (bsel == 2) ? 0 : bsel + 1;
  }
}

// ---------------------------------------------------------------- merge: global top-8
__global__ __launch_bounds__(256) void merge_kernel(
    const uint4* __restrict__ part, int* __restrict__ cand) {
  const int row = blockIdx.x * 256 + threadIdx.x;
  u32 k[NCAND];
#pragma unroll
  for (int i = 0; i < NCAND; ++i) k[i] = ~0u;
  for (int nb = 0; nb < KCODES / 256; ++nb) {
    uint4 e = part[(size_t)nb * M_ROWS + row];
    u32 t = e.x;
#pragma unroll
    for (int i = 0; i < NCAND; ++i) { u32 mx = umax32(k[i], t); k[i] = umin32(k[i], t); t = mx; }
    t = e.y;
#pragma unroll
    for (int i = 0; i < NCAND; ++i) { u32 mx = umax32(k[i], t); k[i] = umin32(k[i], t); t = mx; }
    t = e.z;
#pragma unroll
    for (int i = 0; i < NCAND; ++i) { u32 mx = umax32(k[i], t); k[i] = umin32(k[i], t); t = mx; }
  }
#pragma unroll
  for (int i = 0; i < NCAND; ++i)
    cand[row * NCAND + i] = (int)(k[i] & 0x1FFFu);
}

// ---------------------------------------------------------------- fp32 rescore (8)
__global__ __launch_bounds__(256) void rescore_kernel(
    const float* __restrict__ x, const float* __restrict__ cb,
    const float* __restrict__ cnh, const int* __restrict__ cand,
    int* __restrict__ out) {
  int wave = (blockIdx.x * 256 + threadIdx.x) >> 6;
  int lane = threadIdx.x & 63;
  if (wave >= M_ROWS) return;
  int idx[NCAND];
#pragma unroll
  for (int j = 0; j < NCAND; ++j) idx[j] = cand[wave * NCAND + j];

  const float* xr = x + (size_t)wave * DDIM + lane * 8;
  float4 x0 = *(const float4*)(xr);
  float4 x1 = *(const float4*)(xr + 4);

  float d[NCAND];
#pragma unroll
  for (int j = 0; j < NCAND; ++j) {
    const float* c = cb + (size_t)idx[j] * DDIM + lane * 8;
    float4 a0 = *(const float4*)(c);
    float4 a1 = *(const float4*)(c + 4);
    d[j] = x0.x*a0.x + x0.y*a0.y + x0.z*a0.z + x0.w*a0.w
         + x1.x*a1.x + x1.y*a1.y + x1.z*a1.z + x1.w*a1.w;
  }
#pragma unroll
  for (int off = 32; off; off >>= 1)
#pragma unroll
    for (int j = 0; j < NCAND; ++j) d[j] += __shfl_xor(d[j], off);

  if (lane == 0) {
    u64 best = ~0ull;
#pragma unroll
    for (int j = 0; j < NCAND; ++j) {
      float s = cnh[idx[j]] - d[j];
      u64 key = ((u64)fsort(s) << 32) | (u32)idx[j];  // exact fp32 + np tie-break
      best = umin64(best, key);
    }
    out[wave] = (int)(u32)best;
  }
}

// ---------------------------------------------------------------- launch
extern "C" void kernel_launch(void* const* d_in, const int* in_sizes, int n_in,
                              void* d_out, int out_size, void* d_ws, size_t ws_size,
                              hipStream_t stream) {
  const float* x  = (const float*)d_in[0];
  const float* cb = (const float*)d_in[1];
  int* out = (int*)d_out;

  char* ws = (char*)d_ws;
  unsigned char* ch8  = (unsigned char*)(ws);
  unsigned char* xh8  = (unsigned char*)(ws + (size_t)4 * 1024 * 1024);
  float*         cnh  = (float*)(ws + (size_t)20 * 1024 * 1024);
  int*           cand = (int*)(ws + (size_t)20 * 1024 * 1024 + 32 * 1024);
  uint4*         part = (uint4*)(ws + (size_t)22 * 1024 * 1024);

  conv_codebook_kernel<<<KCODES / 4, 256, 0, stream>>>(cb, ch8, cnh);
  conv_x_kernel<<<(M_ROWS * DDIM) / (256 * 8), 256, 0, stream>>>(x, xh8);
  coarse_kernel<<<(M_ROWS / 128) * 8, 512, 0, stream>>>(xh8, ch8, cnh, part);
  merge_kernel<<<M_ROWS / 256, 256, 0, stream>>>(part, cand);
  rescore_kernel<<<M_ROWS / 4, 256, 0, stream>>>(x, cb, cnh, cand, out);
}